// Round 1
// baseline (97.192 us; speedup 1.0000x reference)
//
#include <hip/hip_runtime.h>

#define T_LEN 512
#define HDIM  32

// One wave handles 2 batch elements: lane = sub*32 + h.
// Each lane owns output unit h of its batch: W_hh row h in VGPRs.
// h-vector circulates through wave-private LDS (broadcast reads).
__global__ void __launch_bounds__(256) rnn_fused(
    const float* __restrict__ x,
    const float* __restrict__ W_ih,
    const float* __restrict__ W_hh,
    const float* __restrict__ b_ih,
    const float* __restrict__ b_hh,
    const float* __restrict__ fc_w,
    const float* __restrict__ fc_b,
    float* __restrict__ out)
{
    // stride 36 floats: 16B-aligned (144B) and half-B lands on bank h+4 (conflict-free vs half-A)
    __shared__ __align__(16) float hbuf[4][2][36];
    __shared__ __align__(16) float xbuf[4][2][32];

    const int tid  = threadIdx.x;
    const int wv   = tid >> 6;
    const int lane = tid & 63;
    const int sub  = lane >> 5;      // which batch within the wave
    const int h    = lane & 31;      // hidden unit owned by this lane
    const int b    = (blockIdx.x << 3) + (wv << 1) + sub;

    // W_hh row h into registers (one-time, cache-served)
    float w[HDIM];
#pragma unroll
    for (int j = 0; j < HDIM; ++j) w[j] = W_hh[h * HDIM + j];
    const float wih  = W_ih[h];
    const float bias = b_ih[h] + b_hh[h];

    const float* xrow = x + (size_t)b * T_LEN;

    float* hw = &hbuf[wv][sub][0];
    float* xw = &xbuf[wv][sub][0];
    const float4* hv4 = (const float4*)hw;

    hw[h] = 0.0f;          // h0 = 0
    xw[h] = xrow[h];       // stage x chunk 0 (t = 0..31)

    float hn = 0.0f;
#pragma unroll 1
    for (int c = 0; c < T_LEN / 32; ++c) {
        float xn = 0.0f;
        const bool more = (c < T_LEN / 32 - 1);
        if (more) xn = xrow[(c + 1) * 32 + h];   // prefetch next x chunk (hidden under 32 steps)
#pragma unroll 8
        for (int tc = 0; tc < 32; ++tc) {
            const float xt = xw[tc];             // broadcast read (uniform per half)
            float a0 = __builtin_fmaf(xt, wih, bias);   // xp = x_t*W_ih[h] + b_ih[h] + b_hh[h]
            float a1 = 0.0f, a2 = 0.0f, a3 = 0.0f;
#pragma unroll
            for (int q = 0; q < 8; ++q) {
                const float4 hv = hv4[q];        // ds_read_b128 broadcast of h[4q..4q+3]
                a0 = __builtin_fmaf(w[4*q+0], hv.x, a0);
                a1 = __builtin_fmaf(w[4*q+1], hv.y, a1);
                a2 = __builtin_fmaf(w[4*q+2], hv.z, a2);
                a3 = __builtin_fmaf(w[4*q+3], hv.w, a3);
            }
            const float y = (a0 + a1) + (a2 + a3);
            // tanh(y) = 1 - 2/(exp(2y)+1); exp(2y) = 2^(y*2*log2(e))
            const float e = __builtin_amdgcn_exp2f(y * 2.8853900817779268f);
            const float r = __builtin_amdgcn_rcpf(e + 1.0f);
            hn = __builtin_fmaf(-2.0f, r, 1.0f);
            hw[h] = hn;                          // publish h_t for next step (same-wave, in-order DS)
        }
        if (more) xw[h] = xn;                    // install prefetched x chunk
    }

    // out[b] = sum_h h_T[h]*fc_w[h] + fc_b   (reduce within each 32-lane half)
    float v = hn * fc_w[h];
#pragma unroll
    for (int m = 16; m >= 1; m >>= 1) v += __shfl_xor(v, m, 64);
    if (h == 0) out[b] = v + fc_b[0];
}

extern "C" void kernel_launch(void* const* d_in, const int* in_sizes, int n_in,
                              void* d_out, int out_size, void* d_ws, size_t ws_size,
                              hipStream_t stream) {
    const float* x    = (const float*)d_in[0];
    const float* W_ih = (const float*)d_in[1];
    const float* W_hh = (const float*)d_in[2];
    const float* b_ih = (const float*)d_in[3];
    const float* b_hh = (const float*)d_in[4];
    const float* fc_w = (const float*)d_in[5];
    const float* fc_b = (const float*)d_in[6];
    float* out = (float*)d_out;

    const int B = out_size;            // 4096
    dim3 grid(B / 8), block(256);      // 8 batch elements per 256-thread block
    hipLaunchKernelGGL(rnn_fused, grid, block, 0, stream,
                       x, W_ih, W_hh, b_ih, b_hh, fc_w, fc_b, out);
}